// Round 7
// baseline (29.208 us; speedup 1.0000x reference)
//
#include <hip/hip_runtime.h>
#include <math.h>

#ifndef M_PI
#define M_PI 3.14159265358979323846
#endif

#define MA 768
#define ROWF (3 * MA)      // 2304 floats per sample row
#define WAVES_PB 2         // samples (waves) per block
#define THREADS (WAVES_PB * 64)

// async global->LDS, 16B per lane: dest = lds_base + lane*16 (linear),
// src = per-lane global address. No VGPR staging -> loads can't be
// serialized by register pressure; all issue back-to-back.
#define GLOAD_LDS16(g, l) __builtin_amdgcn_global_load_lds(              \
    (const __attribute__((address_space(1))) void*)(g),                  \
    (__attribute__((address_space(3))) void*)(l), 16, 0, 0)

// Full-wave (64-lane) sum via DPP on the VALU pipe; total lands in lane 63.
__device__ __forceinline__ float dpp_red_add(float v) {
    v += __int_as_float(__builtin_amdgcn_update_dpp(0, __float_as_int(v), 0x111, 0xf, 0xf, true)); // row_shr:1
    v += __int_as_float(__builtin_amdgcn_update_dpp(0, __float_as_int(v), 0x112, 0xf, 0xf, true)); // row_shr:2
    v += __int_as_float(__builtin_amdgcn_update_dpp(0, __float_as_int(v), 0x114, 0xf, 0xe, true)); // row_shr:4
    v += __int_as_float(__builtin_amdgcn_update_dpp(0, __float_as_int(v), 0x118, 0xf, 0xc, true)); // row_shr:8
    v += __int_as_float(__builtin_amdgcn_update_dpp(0, __float_as_int(v), 0x142, 0xa, 0xf, true)); // row_bcast:15
    v += __int_as_float(__builtin_amdgcn_update_dpp(0, __float_as_int(v), 0x143, 0xc, 0xf, true)); // row_bcast:31
    return v;
}

// ONE kernel: async-stage rows to LDS, atom-aligned LDS reads, DPP reduce,
// fused per-sample eigensolve on lane 63 (f64 — identical numerics to the
// previously-passing epilogue).
__global__ __launch_bounds__(THREADS) void kabsch_kernel(
    const float* __restrict__ inp, const float* __restrict__ tgt,
    const int* __restrict__ natoms, float* __restrict__ out)
{
    __shared__ float lds[WAVES_PB][2 * ROWF];   // 36 864 B
    const int wave = threadIdx.x >> 6;
    const int lane = threadIdx.x & 63;
    const int b = blockIdx.x * WAVES_PB + wave;
    const int n = natoms[b];
    const int nf = 3 * n;                        // valid floats per row

    const float* __restrict__ Xrow = inp + (size_t)b * ROWF;
    const float* __restrict__ Yrow = tgt + (size_t)b * ROWF;
    float* lx = lds[wave];
    float* ly = lds[wave] + ROWF;

    // Stage: 9 chunks x 1024 B per row, wave-uniform validity branch.
#pragma unroll
    for (int k = 0; k < 9; ++k) {
        if (k * 256 < nf) {                      // uniform: no exec divergence
            GLOAD_LDS16(Xrow + k * 256 + 4 * lane, lx + k * 256);
            GLOAD_LDS16(Yrow + k * 256 + 4 * lane, ly + k * 256);
        }
    }
    asm volatile("s_waitcnt vmcnt(0)" ::: "memory");
    __builtin_amdgcn_sched_barrier(0);

    float sx0 = 0.f, sx1 = 0.f, sx2 = 0.f;
    float sy0 = 0.f, sy1 = 0.f, sy2 = 0.f;
    float c00 = 0.f, c01 = 0.f, c02 = 0.f;
    float c10 = 0.f, c11 = 0.f, c12 = 0.f;
    float c20 = 0.f, c21 = 0.f, c22 = 0.f;
    float nx2 = 0.f, ny2 = 0.f;

    // atom a = 64*j + lane; LDS read at 12-B stride (~2-way bank alias, free)
#pragma unroll
    for (int j = 0; j < 12; ++j) {
        const int a = 64 * j + lane;
        float x0 = lx[3 * a + 0], x1 = lx[3 * a + 1], x2 = lx[3 * a + 2];
        float y0 = ly[3 * a + 0], y1 = ly[3 * a + 1], y2 = ly[3 * a + 2];
        if (j >= 6) {                            // n >= 384: j<6 always valid
            const bool v = a < n;
            x0 = v ? x0 : 0.f; x1 = v ? x1 : 0.f; x2 = v ? x2 : 0.f;
            y0 = v ? y0 : 0.f; y1 = v ? y1 : 0.f; y2 = v ? y2 : 0.f;
        }
        sx0 += x0; sx1 += x1; sx2 += x2;
        sy0 += y0; sy1 += y1; sy2 += y2;
        c00 = fmaf(x0, y0, c00); c01 = fmaf(x0, y1, c01); c02 = fmaf(x0, y2, c02);
        c10 = fmaf(x1, y0, c10); c11 = fmaf(x1, y1, c11); c12 = fmaf(x1, y2, c12);
        c20 = fmaf(x2, y0, c20); c21 = fmaf(x2, y1, c21); c22 = fmaf(x2, y2, c22);
        nx2 = fmaf(x0, x0, nx2); nx2 = fmaf(x1, x1, nx2); nx2 = fmaf(x2, x2, nx2);
        ny2 = fmaf(y0, y0, ny2); ny2 = fmaf(y1, y1, ny2); ny2 = fmaf(y2, y2, ny2);
    }

    sx0 = dpp_red_add(sx0); sx1 = dpp_red_add(sx1); sx2 = dpp_red_add(sx2);
    sy0 = dpp_red_add(sy0); sy1 = dpp_red_add(sy1); sy2 = dpp_red_add(sy2);
    c00 = dpp_red_add(c00); c01 = dpp_red_add(c01); c02 = dpp_red_add(c02);
    c10 = dpp_red_add(c10); c11 = dpp_red_add(c11); c12 = dpp_red_add(c12);
    c20 = dpp_red_add(c20); c21 = dpp_red_add(c21); c22 = dpp_red_add(c22);
    nx2 = dpp_red_add(nx2); ny2 = dpp_red_add(ny2);

    // Fused epilogue on lane 63 (f64; ~0.4 us, hidden under other waves' loads)
    if (lane == 63) {
        const double inv_n = 1.0 / (double)n;

        double R00 = (double)c00 - (double)sx0 * (double)sy0 * inv_n;
        double R01 = (double)c01 - (double)sx0 * (double)sy1 * inv_n;
        double R02 = (double)c02 - (double)sx0 * (double)sy2 * inv_n;
        double R10 = (double)c10 - (double)sx1 * (double)sy0 * inv_n;
        double R11 = (double)c11 - (double)sx1 * (double)sy1 * inv_n;
        double R12 = (double)c12 - (double)sx1 * (double)sy2 * inv_n;
        double R20 = (double)c20 - (double)sx2 * (double)sy0 * inv_n;
        double R21 = (double)c21 - (double)sx2 * (double)sy1 * inv_n;
        double R22 = (double)c22 - (double)sx2 * (double)sy2 * inv_n;
        double ex = (double)nx2 -
            ((double)sx0 * sx0 + (double)sx1 * sx1 + (double)sx2 * sx2) * inv_n;
        double ey = (double)ny2 -
            ((double)sy0 * sy0 + (double)sy1 * sy1 + (double)sy2 * sy2) * inv_n;

        double A00 = R00 * R00 + R10 * R10 + R20 * R20;
        double A11 = R01 * R01 + R11 * R11 + R21 * R21;
        double A22 = R02 * R02 + R12 * R12 + R22 * R22;
        double A01 = R00 * R01 + R10 * R11 + R20 * R21;
        double A02 = R00 * R02 + R10 * R12 + R20 * R22;
        double A12 = R01 * R02 + R11 * R12 + R21 * R22;

        double detR = R00 * (R11 * R22 - R12 * R21)
                    - R01 * (R10 * R22 - R12 * R20)
                    + R02 * (R10 * R21 - R11 * R20);

        double q = (A00 + A11 + A22) / 3.0;
        double p1 = A01 * A01 + A02 * A02 + A12 * A12;
        double b00 = A00 - q, b11 = A11 - q, b22 = A22 - q;
        double p2 = b00 * b00 + b11 * b11 + b22 * b22 + 2.0 * p1;
        double e0, e1, e2;
        if (p2 <= 0.0) {
            e0 = e1 = e2 = q;
        } else {
            double p = sqrt(p2 / 6.0);
            double ip = 1.0 / p;
            double B00 = b00 * ip, B11 = b11 * ip, B22 = b22 * ip;
            double B01 = A01 * ip, B02 = A02 * ip, B12 = A12 * ip;
            double detB = B00 * (B11 * B22 - B12 * B12)
                        - B01 * (B01 * B22 - B12 * B02)
                        + B02 * (B01 * B12 - B11 * B02);
            double r = 0.5 * detB;
            r = fmin(1.0, fmax(-1.0, r));
            // trig in f32: error into out ~1e-5 (threshold 5e-2)
            float phi = acosf((float)r) * (1.0f / 3.0f);
            float cA = __cosf(phi);
            float cC = __cosf(phi + (float)(2.0 * M_PI / 3.0));
            e0 = q + 2.0 * p * (double)cA;
            e2 = q + 2.0 * p * (double)cC;
            e1 = 3.0 * q - e0 - e2;
        }
        double s0 = sqrt(fmax(e0, 0.0));
        double s1 = sqrt(fmax(e1, 0.0));
        double s2 = sqrt(fmax(e2, 0.0));
        double d = (detR > 0.0) ? 1.0 : ((detR < 0.0) ? -1.0 : 0.0);
        double tr = s0 + s1 + d * s2;
        double e = ex + ey - 2.0 * tr;
        out[b] = (float)sqrt(fmax(e, 0.0) * inv_n + 1e-7);
    }
}

extern "C" void kernel_launch(void* const* d_in, const int* in_sizes, int n_in,
                              void* d_out, int out_size, void* d_ws, size_t ws_size,
                              hipStream_t stream) {
    const float* inp = (const float*)d_in[0];
    const float* tgt = (const float*)d_in[1];
    const int* natoms = (const int*)d_in[2];
    float* out = (float*)d_out;
    (void)d_ws; (void)ws_size; (void)n_in; (void)in_sizes;
    kabsch_kernel<<<dim3(out_size / WAVES_PB), dim3(THREADS), 0, stream>>>(
        inp, tgt, natoms, out);
}

// Round 8
// 25.129 us; speedup vs baseline: 1.1623x; 1.1623x over previous
//
#include <hip/hip_runtime.h>
#include <math.h>

#ifndef M_PI
#define M_PI 3.14159265358979323846
#endif

#define MA 768   // MAX_ATOMS

// Full-wave (64-lane) sum via DPP on the VALU pipe; total lands in lane 63.
__device__ __forceinline__ float dpp_red_add(float v) {
    v += __int_as_float(__builtin_amdgcn_update_dpp(0, __float_as_int(v), 0x111, 0xf, 0xf, true)); // row_shr:1
    v += __int_as_float(__builtin_amdgcn_update_dpp(0, __float_as_int(v), 0x112, 0xf, 0xf, true)); // row_shr:2
    v += __int_as_float(__builtin_amdgcn_update_dpp(0, __float_as_int(v), 0x114, 0xf, 0xe, true)); // row_shr:4
    v += __int_as_float(__builtin_amdgcn_update_dpp(0, __float_as_int(v), 0x118, 0xf, 0xc, true)); // row_shr:8
    v += __int_as_float(__builtin_amdgcn_update_dpp(0, __float_as_int(v), 0x142, 0xa, 0xf, true)); // row_bcast:15
    v += __int_as_float(__builtin_amdgcn_update_dpp(0, __float_as_int(v), 0x143, 0xc, 0xf, true)); // row_bcast:31
    return v;
}

// ONE kernel, ONE WAVE PER SAMPLE, register path (no LDS).
// 12 atoms/lane; all 18 dwordx4 loads issue in one exec-masked cluster
// (lane active iff its first atom < n), pinned by sched_barrier(0).
// DPP-reduce the 17 sums; lane 63 runs the f64 eigensolve and writes out.
__global__ __launch_bounds__(256, 4) void kabsch_kernel(
    const float* __restrict__ inp, const float* __restrict__ tgt,
    const int* __restrict__ natoms, float* __restrict__ out)
{
    const int wave = threadIdx.x >> 6;
    const int lane = threadIdx.x & 63;
    const int b = blockIdx.x * 4 + wave;
    const int n = natoms[b];
    const float* __restrict__ X = inp + (size_t)b * (3 * MA);
    const float* __restrict__ Y = tgt + (size_t)b * (3 * MA);

    const int a0 = 12 * lane;  // this lane's first atom

    const float4 f4z = make_float4(0.f, 0.f, 0.f, 0.f);
    float4 vx[9], vy[9];
#pragma unroll
    for (int k = 0; k < 9; ++k) { vx[k] = f4z; vy[k] = f4z; }

    if (a0 < n) {  // exec-masked: lanes fully in the invalid tail fetch nothing
        const float4* px = (const float4*)(X + 3 * a0);
        const float4* py = (const float4*)(Y + 3 * a0);
#pragma unroll
        for (int k = 0; k < 9; ++k) vx[k] = px[k];
#pragma unroll
        for (int k = 0; k < 9; ++k) vy[k] = py[k];
    }
    __builtin_amdgcn_sched_barrier(0);  // all 18 loads issue before any consume

    float ax[36], ay[36];
#pragma unroll
    for (int k = 0; k < 9; ++k) {
        *(float4*)&ax[4 * k] = vx[k];
        *(float4*)&ay[4 * k] = vy[k];
    }

    float sx0 = 0.f, sx1 = 0.f, sx2 = 0.f;
    float sy0 = 0.f, sy1 = 0.f, sy2 = 0.f;
    float c00 = 0.f, c01 = 0.f, c02 = 0.f;
    float c10 = 0.f, c11 = 0.f, c12 = 0.f;
    float c20 = 0.f, c21 = 0.f, c22 = 0.f;
    float nx2 = 0.f, ny2 = 0.f;

#pragma unroll
    for (int j = 0; j < 12; ++j) {
        const bool v = (a0 + j) < n;
        const float x0 = v ? ax[3 * j + 0] : 0.f;
        const float x1 = v ? ax[3 * j + 1] : 0.f;
        const float x2 = v ? ax[3 * j + 2] : 0.f;
        const float y0 = v ? ay[3 * j + 0] : 0.f;
        const float y1 = v ? ay[3 * j + 1] : 0.f;
        const float y2 = v ? ay[3 * j + 2] : 0.f;
        sx0 += x0; sx1 += x1; sx2 += x2;
        sy0 += y0; sy1 += y1; sy2 += y2;
        c00 = fmaf(x0, y0, c00); c01 = fmaf(x0, y1, c01); c02 = fmaf(x0, y2, c02);
        c10 = fmaf(x1, y0, c10); c11 = fmaf(x1, y1, c11); c12 = fmaf(x1, y2, c12);
        c20 = fmaf(x2, y0, c20); c21 = fmaf(x2, y1, c21); c22 = fmaf(x2, y2, c22);
        nx2 = fmaf(x0, x0, nx2); nx2 = fmaf(x1, x1, nx2); nx2 = fmaf(x2, x2, nx2);
        ny2 = fmaf(y0, y0, ny2); ny2 = fmaf(y1, y1, ny2); ny2 = fmaf(y2, y2, ny2);
    }

    sx0 = dpp_red_add(sx0); sx1 = dpp_red_add(sx1); sx2 = dpp_red_add(sx2);
    sy0 = dpp_red_add(sy0); sy1 = dpp_red_add(sy1); sy2 = dpp_red_add(sy2);
    c00 = dpp_red_add(c00); c01 = dpp_red_add(c01); c02 = dpp_red_add(c02);
    c10 = dpp_red_add(c10); c11 = dpp_red_add(c11); c12 = dpp_red_add(c12);
    c20 = dpp_red_add(c20); c21 = dpp_red_add(c21); c22 = dpp_red_add(c22);
    nx2 = dpp_red_add(nx2); ny2 = dpp_red_add(ny2);

    // Fused epilogue on lane 63 (f64 products, f32 trig) — same numerics
    // that scored absmax 0.0 in rounds 4-7.
    if (lane == 63) {
        const double inv_n = 1.0 / (double)n;

        double R00 = (double)c00 - (double)sx0 * (double)sy0 * inv_n;
        double R01 = (double)c01 - (double)sx0 * (double)sy1 * inv_n;
        double R02 = (double)c02 - (double)sx0 * (double)sy2 * inv_n;
        double R10 = (double)c10 - (double)sx1 * (double)sy0 * inv_n;
        double R11 = (double)c11 - (double)sx1 * (double)sy1 * inv_n;
        double R12 = (double)c12 - (double)sx1 * (double)sy2 * inv_n;
        double R20 = (double)c20 - (double)sx2 * (double)sy0 * inv_n;
        double R21 = (double)c21 - (double)sx2 * (double)sy1 * inv_n;
        double R22 = (double)c22 - (double)sx2 * (double)sy2 * inv_n;
        double ex = (double)nx2 -
            ((double)sx0 * sx0 + (double)sx1 * sx1 + (double)sx2 * sx2) * inv_n;
        double ey = (double)ny2 -
            ((double)sy0 * sy0 + (double)sy1 * sy1 + (double)sy2 * sy2) * inv_n;

        double A00 = R00 * R00 + R10 * R10 + R20 * R20;
        double A11 = R01 * R01 + R11 * R11 + R21 * R21;
        double A22 = R02 * R02 + R12 * R12 + R22 * R22;
        double A01 = R00 * R01 + R10 * R11 + R20 * R21;
        double A02 = R00 * R02 + R10 * R12 + R20 * R22;
        double A12 = R01 * R02 + R11 * R12 + R21 * R22;

        double detR = R00 * (R11 * R22 - R12 * R21)
                    - R01 * (R10 * R22 - R12 * R20)
                    + R02 * (R10 * R21 - R11 * R20);

        double q = (A00 + A11 + A22) / 3.0;
        double p1 = A01 * A01 + A02 * A02 + A12 * A12;
        double b00 = A00 - q, b11 = A11 - q, b22 = A22 - q;
        double p2 = b00 * b00 + b11 * b11 + b22 * b22 + 2.0 * p1;
        double e0, e1, e2;
        if (p2 <= 0.0) {
            e0 = e1 = e2 = q;
        } else {
            double p = sqrt(p2 / 6.0);
            double ip = 1.0 / p;
            double B00 = b00 * ip, B11 = b11 * ip, B22 = b22 * ip;
            double B01 = A01 * ip, B02 = A02 * ip, B12 = A12 * ip;
            double detB = B00 * (B11 * B22 - B12 * B12)
                        - B01 * (B01 * B22 - B12 * B02)
                        + B02 * (B01 * B12 - B11 * B02);
            double r = 0.5 * detB;
            r = fmin(1.0, fmax(-1.0, r));
            // trig in f32: phi in [0, pi/3]; error into out ~1e-5 (thr 5e-2)
            float phi = acosf((float)r) * (1.0f / 3.0f);
            float cA = __cosf(phi);
            float cC = __cosf(phi + (float)(2.0 * M_PI / 3.0));
            e0 = q + 2.0 * p * (double)cA;
            e2 = q + 2.0 * p * (double)cC;
            e1 = 3.0 * q - e0 - e2;
        }
        double s0 = sqrt(fmax(e0, 0.0));
        double s1 = sqrt(fmax(e1, 0.0));
        double s2 = sqrt(fmax(e2, 0.0));
        double d = (detR > 0.0) ? 1.0 : ((detR < 0.0) ? -1.0 : 0.0);
        double tr = s0 + s1 + d * s2;
        double e = ex + ey - 2.0 * tr;
        out[b] = (float)sqrt(fmax(e, 0.0) * inv_n + 1e-7);
    }
}

extern "C" void kernel_launch(void* const* d_in, const int* in_sizes, int n_in,
                              void* d_out, int out_size, void* d_ws, size_t ws_size,
                              hipStream_t stream) {
    const float* inp = (const float*)d_in[0];
    const float* tgt = (const float*)d_in[1];
    const int* natoms = (const int*)d_in[2];
    float* out = (float*)d_out;
    (void)d_ws; (void)ws_size; (void)n_in; (void)in_sizes;
    kabsch_kernel<<<dim3(out_size / 4), dim3(256), 0, stream>>>(inp, tgt, natoms, out);
}